// Round 9
// baseline (267.466 us; speedup 1.0000x reference)
//
#include <hip/hip_runtime.h>
#include <math.h>

#define NB    4
#define NCLS  5
#define NSHOT 5
#define NQ    75
#define CH    640
#define HW    100
#define SLICE (CH*HW)          // 64000
#define TEMP_INV 4.0f
#define EPSN  1e-12f

typedef float f32x4 __attribute__((ext_vector_type(4)));

// workspace float offsets
#define OFF_PROTO 0            // 1,280,000
#define OFF_PINV  1280000      // 2,000
#define OFF_PBAR  1282000      // 12,800
#define OFF_QINV  1294800      // 30,000
#define OFF_QBAR  1324800      // 192,000
#define OFF_AP    1516800      // 150,000
#define OFF_AQ    1666800      // 150,000

// K1: proto[bn, cc, i] = mean over K shots of fspt
__global__ void k_proto(const float* __restrict__ fspt, float* __restrict__ proto) {
    int v = blockIdx.x * 256 + threadIdx.x;      // float4 index, 320000 total
    if (v >= (NB*NCLS*SLICE)/4) return;
    int p  = v * 4;
    int bn = p / SLICE;
    size_t base = (size_t)bn * NSHOT * SLICE + (p - bn * SLICE);
    f32x4 a = *reinterpret_cast<const f32x4*>(fspt + base);
    for (int k = 1; k < NSHOT; k++)
        a += *reinterpret_cast<const f32x4*>(fspt + base + (size_t)k * SLICE);
    a *= 0.2f;
    *reinterpret_cast<f32x4*>(proto + p) = a;
}

// K2: per-slice stats for proto (blk<20) and fqry (blk>=20).
__global__ void k_stats(const float* __restrict__ proto, const float* __restrict__ fqry,
                        float* __restrict__ pinv, float* __restrict__ pbar,
                        float* __restrict__ qinv, float* __restrict__ qbar) {
    __shared__ float inv_s[HW];
    __shared__ float part_s[256];
    int blk = blockIdx.x;
    bool isP = blk < NB * NCLS;
    int s = isP ? blk : blk - NB * NCLS;
    const float* base = (isP ? proto : fqry) + (size_t)s * SLICE;
    float* inv = (isP ? pinv : qinv) + s * HW;
    float* bar = (isP ? pbar : qbar) + s * CH;
    int t = threadIdx.x;

    float partial = 0.f;
    if (t < 200) {
        int i  = (t < 100) ? t : t - 100;
        int c0 = (t < 100) ? 0 : CH / 2;
        const float* p = base + (size_t)c0 * HW + i;
        #pragma unroll 8
        for (int cc = 0; cc < CH / 2; cc++) { float x = p[cc * HW]; partial += x * x; }
    }
    part_s[t] = partial;
    __syncthreads();
    if (t < HW) {
        float iv = 1.0f / fmaxf(sqrtf(part_s[t] + part_s[t + 100]), EPSN);
        inv_s[t] = iv;
        inv[t] = iv;
    }
    __syncthreads();
    for (int cc = t; cc < CH; cc += 256) {
        float acc = 0.f;
        const f32x4* r = reinterpret_cast<const f32x4*>(base + (size_t)cc * HW);
        #pragma unroll
        for (int i4 = 0; i4 < HW / 4; i4++) {
            f32x4 x = r[i4];
            acc += x.x * inv_s[i4*4] + x.y * inv_s[i4*4+1] + x.z * inv_s[i4*4+2] + x.w * inv_s[i4*4+3];
        }
        bar[cc] = acc * (1.0f / HW);
    }
}

// K3: fused attention maps (R5 form). blk<100 -> ap panel (bn,qg); blk>=100 -> aq panel (bq).
__global__ void k_att(const float* __restrict__ proto, const float* __restrict__ fqry,
                      const float* __restrict__ pinv, const float* __restrict__ pbar,
                      const float* __restrict__ qinv, const float* __restrict__ qbar,
                      float* __restrict__ ap, float* __restrict__ aq) {
    __shared__ float smem[12700];        // 50.8 KB, carved per path
    int blk = blockIdx.x;
    int t = threadIdx.x;
    int w = t >> 6, l = t & 63;

    if (blk < NB * NCLS * 5) {
        // ---- ap panel: (bn, qg), 15 q's ----
        float* qb_s   = smem;             // 15*CH = 9600
        float* part_s = smem + 9600;      // 15*200 = 3000
        float* piv_s  = smem + 12600;     // 100
        int bn = blk / 5;
        int qg = blk - bn * 5;
        int b  = bn / NCLS;

        for (int qq = 0; qq < 15; qq++) {
            int bq = b * NQ + qg * 15 + qq;
            for (int cc = t; cc < CH; cc += 256) qb_s[qq * CH + cc] = qbar[bq * CH + cc];
        }
        if (t < HW) piv_s[t] = pinv[bn * HW + t] * TEMP_INV;
        __syncthreads();

        if (t < 200) {
            int i  = (t < 100) ? t : t - 100;
            int c0 = (t < 100) ? 0 : CH / 2;
            const float* p = proto + (size_t)bn * SLICE + (size_t)c0 * HW + i;
            float acc[15];
            #pragma unroll
            for (int qq = 0; qq < 15; qq++) acc[qq] = 0.f;
            for (int cc = 0; cc < CH / 2; cc++) {
                float pv = p[cc * HW];
                #pragma unroll
                for (int qq = 0; qq < 15; qq++) acc[qq] += pv * qb_s[qq * CH + c0 + cc];
            }
            #pragma unroll
            for (int qq = 0; qq < 15; qq++) part_s[qq * 200 + t] = acc[qq];
        }
        __syncthreads();

        for (int qq = w; qq < 15; qq += 4) {
            float sv0 = (part_s[qq*200 + l] + part_s[qq*200 + l + 100]) * piv_s[l];
            float sv1 = (l < 36) ? (part_s[qq*200 + l + 64] + part_s[qq*200 + l + 164]) * piv_s[l + 64] : -INFINITY;
            float m = fmaxf(sv0, sv1);
            #pragma unroll
            for (int o = 32; o >= 1; o >>= 1) m = fmaxf(m, __shfl_xor(m, o, 64));
            float e0 = __expf(sv0 - m);
            float e1 = (l < 36) ? __expf(sv1 - m) : 0.f;
            float sm = e0 + e1;
            #pragma unroll
            for (int o = 32; o >= 1; o >>= 1) sm += __shfl_xor(sm, o, 64);
            float inv = 1.0f / sm;
            int bqn = (b * NQ + qg * 15 + qq) * NCLS + (bn - b * NCLS);
            float* dst = ap + (size_t)bqn * HW;
            dst[l] = e0 * inv + 1.0f;
            if (l < 36) dst[l + 64] = e1 * inv + 1.0f;
        }
    } else {
        // ---- aq panel: one bq, 5 n's ----
        float* pb_s   = smem;             // NCLS*CH = 3200
        float* part_s = smem + 3200;      // NCLS*200 = 1000
        float* qiv_s  = smem + 4200;      // 100
        int bq = blk - NB * NCLS * 5;
        int b  = bq / NQ;

        for (int k = t; k < NCLS * CH; k += 256) pb_s[k] = pbar[(size_t)b * NCLS * CH + k];
        if (t < HW) qiv_s[t] = qinv[bq * HW + t] * TEMP_INV;
        __syncthreads();

        if (t < 200) {
            int i  = (t < 100) ? t : t - 100;
            int c0 = (t < 100) ? 0 : CH / 2;
            const float* p = fqry + (size_t)bq * SLICE + (size_t)c0 * HW + i;
            float acc[NCLS];
            #pragma unroll
            for (int n = 0; n < NCLS; n++) acc[n] = 0.f;
            for (int cc = 0; cc < CH / 2; cc++) {
                float pv = p[cc * HW];
                #pragma unroll
                for (int n = 0; n < NCLS; n++) acc[n] += pv * pb_s[n * CH + c0 + cc];
            }
            #pragma unroll
            for (int n = 0; n < NCLS; n++) part_s[n * 200 + t] = acc[n];
        }
        __syncthreads();

        for (int n = w; n < NCLS; n += 4) {
            float sv0 = (part_s[n*200 + l] + part_s[n*200 + l + 100]) * qiv_s[l];
            float sv1 = (l < 36) ? (part_s[n*200 + l + 64] + part_s[n*200 + l + 164]) * qiv_s[l + 64] : -INFINITY;
            float m = fmaxf(sv0, sv1);
            #pragma unroll
            for (int o = 32; o >= 1; o >>= 1) m = fmaxf(m, __shfl_xor(m, o, 64));
            float e0 = __expf(sv0 - m);
            float e1 = (l < 36) ? __expf(sv1 - m) : 0.f;
            float sm = e0 + e1;
            #pragma unroll
            for (int o = 32; o >= 1; o >>= 1) sm += __shfl_xor(sm, o, 64);
            float inv = 1.0f / sm;
            int bqn = bq * NCLS + n;
            float* dst = aq + (size_t)bqn * HW;
            dst[l] = e0 * inv + 1.0f;
            if (l < 36) dst[l + 64] = e1 * inv + 1.0f;
        }
    }
}

// K4: output writer (R5 geometry), PLAIN stores (A/B vs nontemporal).
// 128 threads, chunk = 512 floats (125 chunks per slice).
// blk<2500: out0 (bn, chunk): hold proto f4, loop 75 q.
// blk>=2500: out1 (bq, chunk): hold fqry f4, loop 5 n.
__global__ void k_outs(const float* __restrict__ proto, const float* __restrict__ fqry,
                       const float* __restrict__ ap, const float* __restrict__ aq,
                       float* __restrict__ out) {
    const size_t OUT1 = (size_t)NB * NQ * NCLS * SLICE; // 96,000,000
    int blk = blockIdx.x;
    int t = threadIdx.x;

    if (blk < NB * NCLS * 125) {
        int bn = blk / 125;
        int ch = blk - bn * 125;
        int off = ch * 512 + t * 4;
        int i = off % HW;
        int b = bn / NCLS, n = bn - b * NCLS;
        f32x4 pv = *reinterpret_cast<const f32x4*>(proto + (size_t)bn * SLICE + off);
        const float* apb = ap + (size_t)(b * NQ * NCLS + n) * HW + i;
        float* ob = out + (size_t)(b * NQ * NCLS + n) * SLICE + off;
        #pragma unroll 5
        for (int q = 0; q < NQ; q++) {
            f32x4 av = *reinterpret_cast<const f32x4*>(apb + (size_t)q * NCLS * HW);
            f32x4 o = pv * av;
            *reinterpret_cast<f32x4*>(ob + (size_t)q * NCLS * SLICE) = o;
        }
    } else {
        int bb = blk - NB * NCLS * 125;
        int bq = bb / 125;
        int ch = bb - bq * 125;
        int off = ch * 512 + t * 4;
        int i = off % HW;
        f32x4 qv = *reinterpret_cast<const f32x4*>(fqry + (size_t)bq * SLICE + off);
        const float* aqb = aq + (size_t)bq * NCLS * HW + i;
        float* ob = out + OUT1 + (size_t)bq * NCLS * SLICE + off;
        #pragma unroll
        for (int n = 0; n < NCLS; n++) {
            f32x4 av = *reinterpret_cast<const f32x4*>(aqb + n * HW);
            f32x4 o = qv * av;
            *reinterpret_cast<f32x4*>(ob + (size_t)n * SLICE) = o;
        }
    }
}

extern "C" void kernel_launch(void* const* d_in, const int* in_sizes, int n_in,
                              void* d_out, int out_size, void* d_ws, size_t ws_size,
                              hipStream_t stream) {
    const float* fspt = (const float*)d_in[0];
    const float* fqry = (const float*)d_in[1];
    float* ws  = (float*)d_ws;
    float* out = (float*)d_out;

    float* proto = ws + OFF_PROTO;
    float* pinv  = ws + OFF_PINV;
    float* pbar  = ws + OFF_PBAR;
    float* qinv  = ws + OFF_QINV;
    float* qbar  = ws + OFF_QBAR;
    float* ap    = ws + OFF_AP;
    float* aq    = ws + OFF_AQ;

    k_proto<<<1250, 256, 0, stream>>>(fspt, proto);
    k_stats<<<NB * NCLS + NB * NQ, 256, 0, stream>>>(proto, fqry, pinv, pbar, qinv, qbar);
    k_att<<<NB * NCLS * 5 + NB * NQ, 256, 0, stream>>>(proto, fqry, pinv, pbar, qinv, qbar, ap, aq);
    k_outs<<<NB * NCLS * 125 + NB * NQ * 125, 128, 0, stream>>>(proto, fqry, ap, aq, out);
}

// Round 10
// 234.184 us; speedup vs baseline: 1.1421x; 1.1421x over previous
//
#include <hip/hip_runtime.h>
#include <math.h>

#define NB    4
#define NCLS  5
#define NSHOT 5
#define NQ    75
#define CH    640
#define HW    100
#define SLICE (CH*HW)          // 64000
#define TEMP_INV 4.0f
#define EPSN  1e-12f

typedef float f32x4 __attribute__((ext_vector_type(4)));

// workspace float offsets
#define OFF_PROTO 0            // 1,280,000
#define OFF_PINV  1280000      // 2,000
#define OFF_PBAR  1282000      // 12,800
#define OFF_QINV  1294800      // 30,000
#define OFF_QBAR  1324800      // 192,000
#define OFF_AP    1516800      // 150,000
#define OFF_AQ    1666800      // 150,000

// K1: merged proto-mean + stats. 320 blocks.
// blk<20: proto slice bn — compute proto=mean_k(fspt) inline (f4), write it,
//         accumulate column norms from registers, then bar from L2 re-read.
// blk>=20: fqry slice bq — f4 column norms, then bar.
// Phase-1 layout: t<250: g=t/25 (c-slice of 64 ch), r=t%25 (i4 group of 4 i's).
__global__ void k_prep(const float* __restrict__ fspt, const float* __restrict__ fqry,
                       float* __restrict__ proto,
                       float* __restrict__ pinv, float* __restrict__ pbar,
                       float* __restrict__ qinv, float* __restrict__ qbar) {
    __shared__ f32x4 part4_s[250];
    __shared__ float inv_s[HW];
    int blk = blockIdx.x;
    int t = threadIdx.x;
    bool isP = blk < NB * NCLS;
    int s = isP ? blk : blk - NB * NCLS;
    int g = t / 25, r = t - g * 25;

    f32x4 partial = {0.f, 0.f, 0.f, 0.f};
    if (t < 250) {
        if (isP) {
            const float* base = fspt + (size_t)s * NSHOT * SLICE;
            float* pdst = proto + (size_t)s * SLICE;
            #pragma unroll 8
            for (int k = 0; k < 64; k++) {
                int cc = g * 64 + k;
                const float* col = base + cc * HW + r * 4;
                f32x4 pm = *reinterpret_cast<const f32x4*>(col);
                pm += *reinterpret_cast<const f32x4*>(col + SLICE);
                pm += *reinterpret_cast<const f32x4*>(col + 2 * SLICE);
                pm += *reinterpret_cast<const f32x4*>(col + 3 * SLICE);
                pm += *reinterpret_cast<const f32x4*>(col + 4 * SLICE);
                pm *= 0.2f;
                *reinterpret_cast<f32x4*>(pdst + cc * HW + r * 4) = pm;
                partial += pm * pm;
            }
        } else {
            const float* base = fqry + (size_t)s * SLICE;
            #pragma unroll 8
            for (int k = 0; k < 64; k++) {
                int cc = g * 64 + k;
                f32x4 x = *reinterpret_cast<const f32x4*>(base + cc * HW + r * 4);
                partial += x * x;
            }
        }
        part4_s[t] = partial;
    }
    __syncthreads();

    float* inv = (isP ? pinv : qinv) + s * HW;
    if (t < HW) {
        int rr = t >> 2, jj = t & 3;
        float acc = 0.f;
        #pragma unroll
        for (int gg = 0; gg < 10; gg++) acc += part4_s[gg * 25 + rr][jj];
        float iv = 1.0f / fmaxf(sqrtf(acc), EPSN);
        inv_s[t] = iv;
        inv[t] = iv;
    }
    __syncthreads();

    const float* rowbase = isP ? (proto + (size_t)s * SLICE) : (fqry + (size_t)s * SLICE);
    float* bar = (isP ? pbar : qbar) + s * CH;
    for (int cc = t; cc < CH; cc += 256) {
        float acc = 0.f;
        const f32x4* r4 = reinterpret_cast<const f32x4*>(rowbase + (size_t)cc * HW);
        #pragma unroll
        for (int i4 = 0; i4 < HW / 4; i4++) {
            f32x4 x = r4[i4];
            acc += x.x * inv_s[i4*4] + x.y * inv_s[i4*4+1] + x.z * inv_s[i4*4+2] + x.w * inv_s[i4*4+3];
        }
        bar[cc] = acc * (1.0f / HW);
    }
}

// K2: fused attention maps (R5 form). blk<100 -> ap panel (bn,qg); blk>=100 -> aq panel (bq).
__global__ void k_att(const float* __restrict__ proto, const float* __restrict__ fqry,
                      const float* __restrict__ pinv, const float* __restrict__ pbar,
                      const float* __restrict__ qinv, const float* __restrict__ qbar,
                      float* __restrict__ ap, float* __restrict__ aq) {
    __shared__ float smem[12700];        // 50.8 KB, carved per path
    int blk = blockIdx.x;
    int t = threadIdx.x;
    int w = t >> 6, l = t & 63;

    if (blk < NB * NCLS * 5) {
        // ---- ap panel: (bn, qg), 15 q's ----
        float* qb_s   = smem;             // 15*CH = 9600
        float* part_s = smem + 9600;      // 15*200 = 3000
        float* piv_s  = smem + 12600;     // 100
        int bn = blk / 5;
        int qg = blk - bn * 5;
        int b  = bn / NCLS;

        for (int qq = 0; qq < 15; qq++) {
            int bq = b * NQ + qg * 15 + qq;
            for (int cc = t; cc < CH; cc += 256) qb_s[qq * CH + cc] = qbar[bq * CH + cc];
        }
        if (t < HW) piv_s[t] = pinv[bn * HW + t] * TEMP_INV;
        __syncthreads();

        if (t < 200) {
            int i  = (t < 100) ? t : t - 100;
            int c0 = (t < 100) ? 0 : CH / 2;
            const float* p = proto + (size_t)bn * SLICE + (size_t)c0 * HW + i;
            float acc[15];
            #pragma unroll
            for (int qq = 0; qq < 15; qq++) acc[qq] = 0.f;
            for (int cc = 0; cc < CH / 2; cc++) {
                float pv = p[cc * HW];
                #pragma unroll
                for (int qq = 0; qq < 15; qq++) acc[qq] += pv * qb_s[qq * CH + c0 + cc];
            }
            #pragma unroll
            for (int qq = 0; qq < 15; qq++) part_s[qq * 200 + t] = acc[qq];
        }
        __syncthreads();

        for (int qq = w; qq < 15; qq += 4) {
            float sv0 = (part_s[qq*200 + l] + part_s[qq*200 + l + 100]) * piv_s[l];
            float sv1 = (l < 36) ? (part_s[qq*200 + l + 64] + part_s[qq*200 + l + 164]) * piv_s[l + 64] : -INFINITY;
            float m = fmaxf(sv0, sv1);
            #pragma unroll
            for (int o = 32; o >= 1; o >>= 1) m = fmaxf(m, __shfl_xor(m, o, 64));
            float e0 = __expf(sv0 - m);
            float e1 = (l < 36) ? __expf(sv1 - m) : 0.f;
            float sm = e0 + e1;
            #pragma unroll
            for (int o = 32; o >= 1; o >>= 1) sm += __shfl_xor(sm, o, 64);
            float inv = 1.0f / sm;
            int bqn = (b * NQ + qg * 15 + qq) * NCLS + (bn - b * NCLS);
            float* dst = ap + (size_t)bqn * HW;
            dst[l] = e0 * inv + 1.0f;
            if (l < 36) dst[l + 64] = e1 * inv + 1.0f;
        }
    } else {
        // ---- aq panel: one bq, 5 n's ----
        float* pb_s   = smem;             // NCLS*CH = 3200
        float* part_s = smem + 3200;      // NCLS*200 = 1000
        float* qiv_s  = smem + 4200;      // 100
        int bq = blk - NB * NCLS * 5;
        int b  = bq / NQ;

        for (int k = t; k < NCLS * CH; k += 256) pb_s[k] = pbar[(size_t)b * NCLS * CH + k];
        if (t < HW) qiv_s[t] = qinv[bq * HW + t] * TEMP_INV;
        __syncthreads();

        if (t < 200) {
            int i  = (t < 100) ? t : t - 100;
            int c0 = (t < 100) ? 0 : CH / 2;
            const float* p = fqry + (size_t)bq * SLICE + (size_t)c0 * HW + i;
            float acc[NCLS];
            #pragma unroll
            for (int n = 0; n < NCLS; n++) acc[n] = 0.f;
            for (int cc = 0; cc < CH / 2; cc++) {
                float pv = p[cc * HW];
                #pragma unroll
                for (int n = 0; n < NCLS; n++) acc[n] += pv * pb_s[n * CH + c0 + cc];
            }
            #pragma unroll
            for (int n = 0; n < NCLS; n++) part_s[n * 200 + t] = acc[n];
        }
        __syncthreads();

        for (int n = w; n < NCLS; n += 4) {
            float sv0 = (part_s[n*200 + l] + part_s[n*200 + l + 100]) * qiv_s[l];
            float sv1 = (l < 36) ? (part_s[n*200 + l + 64] + part_s[n*200 + l + 164]) * qiv_s[l + 64] : -INFINITY;
            float m = fmaxf(sv0, sv1);
            #pragma unroll
            for (int o = 32; o >= 1; o >>= 1) m = fmaxf(m, __shfl_xor(m, o, 64));
            float e0 = __expf(sv0 - m);
            float e1 = (l < 36) ? __expf(sv1 - m) : 0.f;
            float sm = e0 + e1;
            #pragma unroll
            for (int o = 32; o >= 1; o >>= 1) sm += __shfl_xor(sm, o, 64);
            float inv = 1.0f / sm;
            int bqn = bq * NCLS + n;
            float* dst = aq + (size_t)bqn * HW;
            dst[l] = e0 * inv + 1.0f;
            if (l < 36) dst[l + 64] = e1 * inv + 1.0f;
        }
    }
}

// K3: output writer (R5 geometry, nontemporal stores).
// 128 threads, chunk = 512 floats (125 chunks per slice).
// blk<2500: out0 (bn, chunk): hold proto f4, loop 75 q.
// blk>=2500: out1 (bq, chunk): hold fqry f4, loop 5 n.
__global__ void k_outs(const float* __restrict__ proto, const float* __restrict__ fqry,
                       const float* __restrict__ ap, const float* __restrict__ aq,
                       float* __restrict__ out) {
    const size_t OUT1 = (size_t)NB * NQ * NCLS * SLICE; // 96,000,000
    int blk = blockIdx.x;
    int t = threadIdx.x;

    if (blk < NB * NCLS * 125) {
        int bn = blk / 125;
        int ch = blk - bn * 125;
        int off = ch * 512 + t * 4;
        int i = off % HW;
        int b = bn / NCLS, n = bn - b * NCLS;
        f32x4 pv = *reinterpret_cast<const f32x4*>(proto + (size_t)bn * SLICE + off);
        const float* apb = ap + (size_t)(b * NQ * NCLS + n) * HW + i;
        float* ob = out + (size_t)(b * NQ * NCLS + n) * SLICE + off;
        #pragma unroll 5
        for (int q = 0; q < NQ; q++) {
            f32x4 av = *reinterpret_cast<const f32x4*>(apb + (size_t)q * NCLS * HW);
            f32x4 o = pv * av;
            __builtin_nontemporal_store(o, reinterpret_cast<f32x4*>(ob + (size_t)q * NCLS * SLICE));
        }
    } else {
        int bb = blk - NB * NCLS * 125;
        int bq = bb / 125;
        int ch = bb - bq * 125;
        int off = ch * 512 + t * 4;
        int i = off % HW;
        f32x4 qv = *reinterpret_cast<const f32x4*>(fqry + (size_t)bq * SLICE + off);
        const float* aqb = aq + (size_t)bq * NCLS * HW + i;
        float* ob = out + OUT1 + (size_t)bq * NCLS * SLICE + off;
        #pragma unroll
        for (int n = 0; n < NCLS; n++) {
            f32x4 av = *reinterpret_cast<const f32x4*>(aqb + n * HW);
            f32x4 o = qv * av;
            __builtin_nontemporal_store(o, reinterpret_cast<f32x4*>(ob + (size_t)n * SLICE));
        }
    }
}

extern "C" void kernel_launch(void* const* d_in, const int* in_sizes, int n_in,
                              void* d_out, int out_size, void* d_ws, size_t ws_size,
                              hipStream_t stream) {
    const float* fspt = (const float*)d_in[0];
    const float* fqry = (const float*)d_in[1];
    float* ws  = (float*)d_ws;
    float* out = (float*)d_out;

    float* proto = ws + OFF_PROTO;
    float* pinv  = ws + OFF_PINV;
    float* pbar  = ws + OFF_PBAR;
    float* qinv  = ws + OFF_QINV;
    float* qbar  = ws + OFF_QBAR;
    float* ap    = ws + OFF_AP;
    float* aq    = ws + OFF_AQ;

    k_prep<<<NB * NCLS + NB * NQ, 256, 0, stream>>>(fspt, fqry, proto, pinv, pbar, qinv, qbar);
    k_att<<<NB * NCLS * 5 + NB * NQ, 256, 0, stream>>>(proto, fqry, pinv, pbar, qinv, qbar, ap, aq);
    k_outs<<<NB * NCLS * 125 + NB * NQ * 125, 128, 0, stream>>>(proto, fqry, ap, aq, out);
}

// Round 11
// 228.817 us; speedup vs baseline: 1.1689x; 1.0235x over previous
//
#include <hip/hip_runtime.h>
#include <math.h>

#define NB    4
#define NCLS  5
#define NSHOT 5
#define NQ    75
#define CH    640
#define HW    100
#define SLICE (CH*HW)          // 64000
#define TEMP_INV 4.0f
#define EPSN  1e-12f

typedef float f32x4 __attribute__((ext_vector_type(4)));

// workspace float offsets
#define OFF_PROTO 0            // 1,280,000
#define OFF_PINV  1280000      // 2,000
#define OFF_PBAR  1282000      // 12,800
#define OFF_QINV  1294800      // 30,000
#define OFF_QBAR  1324800      // 192,000
#define OFF_AP    1516800      // 150,000
#define OFF_AQ    1666800      // 150,000

// K1: proto[bn, cc, i] = mean over K shots of fspt
__global__ void k_proto(const float* __restrict__ fspt, float* __restrict__ proto) {
    int v = blockIdx.x * 256 + threadIdx.x;      // float4 index, 320000 total
    if (v >= (NB*NCLS*SLICE)/4) return;
    int p  = v * 4;
    int bn = p / SLICE;
    size_t base = (size_t)bn * NSHOT * SLICE + (p - bn * SLICE);
    f32x4 a = *reinterpret_cast<const f32x4*>(fspt + base);
    for (int k = 1; k < NSHOT; k++)
        a += *reinterpret_cast<const f32x4*>(fspt + base + (size_t)k * SLICE);
    a *= 0.2f;
    *reinterpret_cast<f32x4*>(proto + p) = a;
}

// K2: per-slice stats for proto (blk<20) and fqry (blk>=20).
__global__ void k_stats(const float* __restrict__ proto, const float* __restrict__ fqry,
                        float* __restrict__ pinv, float* __restrict__ pbar,
                        float* __restrict__ qinv, float* __restrict__ qbar) {
    __shared__ float inv_s[HW];
    __shared__ float part_s[256];
    int blk = blockIdx.x;
    bool isP = blk < NB * NCLS;
    int s = isP ? blk : blk - NB * NCLS;
    const float* base = (isP ? proto : fqry) + (size_t)s * SLICE;
    float* inv = (isP ? pinv : qinv) + s * HW;
    float* bar = (isP ? pbar : qbar) + s * CH;
    int t = threadIdx.x;

    float partial = 0.f;
    if (t < 200) {
        int i  = (t < 100) ? t : t - 100;
        int c0 = (t < 100) ? 0 : CH / 2;
        const float* p = base + (size_t)c0 * HW + i;
        #pragma unroll 8
        for (int cc = 0; cc < CH / 2; cc++) { float x = p[cc * HW]; partial += x * x; }
    }
    part_s[t] = partial;
    __syncthreads();
    if (t < HW) {
        float iv = 1.0f / fmaxf(sqrtf(part_s[t] + part_s[t + 100]), EPSN);
        inv_s[t] = iv;
        inv[t] = iv;
    }
    __syncthreads();
    for (int cc = t; cc < CH; cc += 256) {
        float acc = 0.f;
        const f32x4* r = reinterpret_cast<const f32x4*>(base + (size_t)cc * HW);
        #pragma unroll
        for (int i4 = 0; i4 < HW / 4; i4++) {
            f32x4 x = r[i4];
            acc += x.x * inv_s[i4*4] + x.y * inv_s[i4*4+1] + x.z * inv_s[i4*4+2] + x.w * inv_s[i4*4+3];
        }
        bar[cc] = acc * (1.0f / HW);
    }
}

// K3: fused attention maps. blk<100 -> ap panel (bn,qg); blk>=100 -> aq panel (bq).
__global__ void k_att(const float* __restrict__ proto, const float* __restrict__ fqry,
                      const float* __restrict__ pinv, const float* __restrict__ pbar,
                      const float* __restrict__ qinv, const float* __restrict__ qbar,
                      float* __restrict__ ap, float* __restrict__ aq) {
    __shared__ float smem[12700];        // 50.8 KB, carved per path
    int blk = blockIdx.x;
    int t = threadIdx.x;
    int w = t >> 6, l = t & 63;

    if (blk < NB * NCLS * 5) {
        // ---- ap panel: (bn, qg), 15 q's ----
        float* qb_s   = smem;             // 15*CH = 9600
        float* part_s = smem + 9600;      // 15*200 = 3000
        float* piv_s  = smem + 12600;     // 100
        int bn = blk / 5;
        int qg = blk - bn * 5;
        int b  = bn / NCLS;

        for (int qq = 0; qq < 15; qq++) {
            int bq = b * NQ + qg * 15 + qq;
            for (int cc = t; cc < CH; cc += 256) qb_s[qq * CH + cc] = qbar[bq * CH + cc];
        }
        if (t < HW) piv_s[t] = pinv[bn * HW + t] * TEMP_INV;
        __syncthreads();

        if (t < 200) {
            int i  = (t < 100) ? t : t - 100;
            int c0 = (t < 100) ? 0 : CH / 2;
            const float* p = proto + (size_t)bn * SLICE + (size_t)c0 * HW + i;
            float acc[15];
            #pragma unroll
            for (int qq = 0; qq < 15; qq++) acc[qq] = 0.f;
            for (int cc = 0; cc < CH / 2; cc++) {
                float pv = p[cc * HW];
                #pragma unroll
                for (int qq = 0; qq < 15; qq++) acc[qq] += pv * qb_s[qq * CH + c0 + cc];
            }
            #pragma unroll
            for (int qq = 0; qq < 15; qq++) part_s[qq * 200 + t] = acc[qq];
        }
        __syncthreads();

        for (int qq = w; qq < 15; qq += 4) {
            float sv0 = (part_s[qq*200 + l] + part_s[qq*200 + l + 100]) * piv_s[l];
            float sv1 = (l < 36) ? (part_s[qq*200 + l + 64] + part_s[qq*200 + l + 164]) * piv_s[l + 64] : -INFINITY;
            float m = fmaxf(sv0, sv1);
            #pragma unroll
            for (int o = 32; o >= 1; o >>= 1) m = fmaxf(m, __shfl_xor(m, o, 64));
            float e0 = __expf(sv0 - m);
            float e1 = (l < 36) ? __expf(sv1 - m) : 0.f;
            float sm = e0 + e1;
            #pragma unroll
            for (int o = 32; o >= 1; o >>= 1) sm += __shfl_xor(sm, o, 64);
            float inv = 1.0f / sm;
            int bqn = (b * NQ + qg * 15 + qq) * NCLS + (bn - b * NCLS);
            float* dst = ap + (size_t)bqn * HW;
            dst[l] = e0 * inv + 1.0f;
            if (l < 36) dst[l + 64] = e1 * inv + 1.0f;
        }
    } else {
        // ---- aq panel: one bq, 5 n's ----
        float* pb_s   = smem;             // NCLS*CH = 3200
        float* part_s = smem + 3200;      // NCLS*200 = 1000
        float* qiv_s  = smem + 4200;      // 100
        int bq = blk - NB * NCLS * 5;
        int b  = bq / NQ;

        for (int k = t; k < NCLS * CH; k += 256) pb_s[k] = pbar[(size_t)b * NCLS * CH + k];
        if (t < HW) qiv_s[t] = qinv[bq * HW + t] * TEMP_INV;
        __syncthreads();

        if (t < 200) {
            int i  = (t < 100) ? t : t - 100;
            int c0 = (t < 100) ? 0 : CH / 2;
            const float* p = fqry + (size_t)bq * SLICE + (size_t)c0 * HW + i;
            float acc[NCLS];
            #pragma unroll
            for (int n = 0; n < NCLS; n++) acc[n] = 0.f;
            for (int cc = 0; cc < CH / 2; cc++) {
                float pv = p[cc * HW];
                #pragma unroll
                for (int n = 0; n < NCLS; n++) acc[n] += pv * pb_s[n * CH + c0 + cc];
            }
            #pragma unroll
            for (int n = 0; n < NCLS; n++) part_s[n * 200 + t] = acc[n];
        }
        __syncthreads();

        for (int n = w; n < NCLS; n += 4) {
            float sv0 = (part_s[n*200 + l] + part_s[n*200 + l + 100]) * qiv_s[l];
            float sv1 = (l < 36) ? (part_s[n*200 + l + 64] + part_s[n*200 + l + 164]) * qiv_s[l + 64] : -INFINITY;
            float m = fmaxf(sv0, sv1);
            #pragma unroll
            for (int o = 32; o >= 1; o >>= 1) m = fmaxf(m, __shfl_xor(m, o, 64));
            float e0 = __expf(sv0 - m);
            float e1 = (l < 36) ? __expf(sv1 - m) : 0.f;
            float sm = e0 + e1;
            #pragma unroll
            for (int o = 32; o >= 1; o >>= 1) sm += __shfl_xor(sm, o, 64);
            float inv = 1.0f / sm;
            int bqn = bq * NCLS + n;
            float* dst = aq + (size_t)bqn * HW;
            dst[l] = e0 * inv + 1.0f;
            if (l < 36) dst[l + 64] = e1 * inv + 1.0f;
        }
    }
}

// K4: fused output writer, register-held input, broadcast loop, nontemporal stores.
// blk<2500: out0 (bn, chunk): hold proto f4, loop 75 q.
// blk>=2500: out1 (bq, chunk): hold fqry f4, loop 5 n.
// 128 threads, chunk = 512 floats (125 chunks per slice).
__global__ void k_outs(const float* __restrict__ proto, const float* __restrict__ fqry,
                       const float* __restrict__ ap, const float* __restrict__ aq,
                       float* __restrict__ out) {
    const size_t OUT1 = (size_t)NB * NQ * NCLS * SLICE; // 96,000,000
    int blk = blockIdx.x;
    int t = threadIdx.x;

    if (blk < NB * NCLS * 125) {
        int bn = blk / 125;
        int ch = blk - bn * 125;
        int off = ch * 512 + t * 4;
        int i = off % HW;
        int b = bn / NCLS, n = bn - b * NCLS;
        f32x4 pv = *reinterpret_cast<const f32x4*>(proto + (size_t)bn * SLICE + off);
        const float* apb = ap + (size_t)(b * NQ * NCLS + n) * HW + i;
        float* ob = out + (size_t)(b * NQ * NCLS + n) * SLICE + off;
        #pragma unroll 5
        for (int q = 0; q < NQ; q++) {
            f32x4 av = *reinterpret_cast<const f32x4*>(apb + (size_t)q * NCLS * HW);
            f32x4 o = pv * av;
            __builtin_nontemporal_store(o, reinterpret_cast<f32x4*>(ob + (size_t)q * NCLS * SLICE));
        }
    } else {
        int bb = blk - NB * NCLS * 125;
        int bq = bb / 125;
        int ch = bb - bq * 125;
        int off = ch * 512 + t * 4;
        int i = off % HW;
        f32x4 qv = *reinterpret_cast<const f32x4*>(fqry + (size_t)bq * SLICE + off);
        const float* aqb = aq + (size_t)bq * NCLS * HW + i;
        float* ob = out + OUT1 + (size_t)bq * NCLS * SLICE + off;
        #pragma unroll
        for (int n = 0; n < NCLS; n++) {
            f32x4 av = *reinterpret_cast<const f32x4*>(aqb + n * HW);
            f32x4 o = qv * av;
            __builtin_nontemporal_store(o, reinterpret_cast<f32x4*>(ob + (size_t)n * SLICE));
        }
    }
}

extern "C" void kernel_launch(void* const* d_in, const int* in_sizes, int n_in,
                              void* d_out, int out_size, void* d_ws, size_t ws_size,
                              hipStream_t stream) {
    const float* fspt = (const float*)d_in[0];
    const float* fqry = (const float*)d_in[1];
    float* ws  = (float*)d_ws;
    float* out = (float*)d_out;

    float* proto = ws + OFF_PROTO;
    float* pinv  = ws + OFF_PINV;
    float* pbar  = ws + OFF_PBAR;
    float* qinv  = ws + OFF_QINV;
    float* qbar  = ws + OFF_QBAR;
    float* ap    = ws + OFF_AP;
    float* aq    = ws + OFF_AQ;

    k_proto<<<1250, 256, 0, stream>>>(fspt, proto);
    k_stats<<<NB * NCLS + NB * NQ, 256, 0, stream>>>(proto, fqry, pinv, pbar, qinv, qbar);
    k_att<<<NB * NCLS * 5 + NB * NQ, 256, 0, stream>>>(proto, fqry, pinv, pbar, qinv, qbar, ap, aq);
    k_outs<<<NB * NCLS * 125 + NB * NQ * 125, 128, 0, stream>>>(proto, fqry, ap, aq, out);
}